// Round 9
// baseline (144.481 us; speedup 1.0000x reference)
//
#include <hip/hip_runtime.h>
#include <float.h>
#include <math.h>

#define Bn 8
#define Cn 256
#define Hn 160
#define Wn 160
#define HWn (Hn * Wn)          // 25600
#define NPIX (Bn * HWn)        // 204800
#define PBLK 256               // pixels per block
#define BLKS (NPIX / PBLK)     // 800

typedef float v4f __attribute__((ext_vector_type(4)));

// Single fused kernel, flag-pipelined (no cooperative launch, no grid barrier):
//  phase 1: block reduces its 256 pixels over 256 channels -> desc written with
//           agent-scope (write-through) stores, then release-store flag[bid].
//  wait:    acquire-spin on flag[bid-2 .. bid+2] (conv halo = 3 rows = 483 px
//           < 2 blocks); lanes 0..4 spin, rest of block parks at syncthreads.
//  phase 2: conv7+conv3+sigmoid from desc (agent-scope tap loads, so no
//           stale-L1/L2 reads -> no cache-wide invalidates needed), then
//           out = x*w. x re-read hits the Infinity Cache (proven by R7's
//           FETCH=1x); NT stores keep out from evicting x.
__global__ __launch_bounds__(256) void k_fused(const float* __restrict__ x,
                                               const float* __restrict__ w7,
                                               const float* __restrict__ w3,
                                               const float* __restrict__ alphap,
                                               float* __restrict__ avgp,
                                               float* __restrict__ maxp,
                                               int* __restrict__ flags,
                                               float* __restrict__ out) {
    const int tid  = threadIdx.x;
    const int lane = tid & 63;
    const int wv   = tid >> 6;
    const int bid  = blockIdx.x;
    const int base = bid << 8;           // first pixel of this block
    const int b    = base / HWn;
    const int hwb  = base - b * HWn;
    const int c0   = wv << 6;
    const size_t off0 = (size_t)b * Cn * HWn + hwb + (lane << 2);

    // ---------------- Phase 1: per-pixel channel mean + max ----------------
    {
        const float* xp = x + off0;
        float4 s = make_float4(0.f, 0.f, 0.f, 0.f);
        float4 m = make_float4(-FLT_MAX, -FLT_MAX, -FLT_MAX, -FLT_MAX);
        #pragma unroll 8
        for (int c = 0; c < 64; ++c) {
            const float4 v = *reinterpret_cast<const float4*>(xp + (size_t)(c0 + c) * HWn);
            s.x += v.x; s.y += v.y; s.z += v.z; s.w += v.w;
            m.x = fmaxf(m.x, v.x); m.y = fmaxf(m.y, v.y);
            m.z = fmaxf(m.z, v.z); m.w = fmaxf(m.w, v.w);
        }

        __shared__ float4 ss[4][64];
        __shared__ float4 sm[4][64];
        ss[wv][lane] = s;
        sm[wv][lane] = m;
        __syncthreads();

        if (tid < 64) {
            const float4 s0 = ss[0][tid], s1 = ss[1][tid], s2 = ss[2][tid], s3 = ss[3][tid];
            const float4 m0 = sm[0][tid], m1 = sm[1][tid], m2 = sm[2][tid], m3 = sm[3][tid];
            const float inv = 1.0f / (float)Cn;
            float4 av, mx;
            av.x = (s0.x + s1.x + s2.x + s3.x) * inv;
            av.y = (s0.y + s1.y + s2.y + s3.y) * inv;
            av.z = (s0.z + s1.z + s2.z + s3.z) * inv;
            av.w = (s0.w + s1.w + s2.w + s3.w) * inv;
            mx.x = fmaxf(fmaxf(m0.x, m1.x), fmaxf(m2.x, m3.x));
            mx.y = fmaxf(fmaxf(m0.y, m1.y), fmaxf(m2.y, m3.y));
            mx.z = fmaxf(fmaxf(m0.z, m1.z), fmaxf(m2.z, m3.z));
            mx.w = fmaxf(fmaxf(m0.w, m1.w), fmaxf(m2.w, m3.w));
            // Agent-scope write-through stores: device-visible once retired,
            // no dirty state stranded in this XCD's L2.
            const int p = base + (tid << 2);
            __hip_atomic_store(&avgp[p+0], av.x, __ATOMIC_RELAXED, __HIP_MEMORY_SCOPE_AGENT);
            __hip_atomic_store(&avgp[p+1], av.y, __ATOMIC_RELAXED, __HIP_MEMORY_SCOPE_AGENT);
            __hip_atomic_store(&avgp[p+2], av.z, __ATOMIC_RELAXED, __HIP_MEMORY_SCOPE_AGENT);
            __hip_atomic_store(&avgp[p+3], av.w, __ATOMIC_RELAXED, __HIP_MEMORY_SCOPE_AGENT);
            __hip_atomic_store(&maxp[p+0], mx.x, __ATOMIC_RELAXED, __HIP_MEMORY_SCOPE_AGENT);
            __hip_atomic_store(&maxp[p+1], mx.y, __ATOMIC_RELAXED, __HIP_MEMORY_SCOPE_AGENT);
            __hip_atomic_store(&maxp[p+2], mx.z, __ATOMIC_RELAXED, __HIP_MEMORY_SCOPE_AGENT);
            __hip_atomic_store(&maxp[p+3], mx.w, __ATOMIC_RELAXED, __HIP_MEMORY_SCOPE_AGENT);
        }
    }

    // All threads' desc stores retired before anyone passes this barrier
    // (compiler drains vmcnt before s_barrier), so release the flag.
    __syncthreads();
    if (tid == 0) {
        __hip_atomic_store(&flags[bid], 1, __ATOMIC_RELEASE, __HIP_MEMORY_SCOPE_AGENT);
    }
    // Wait for halo neighbors (bid-2 .. bid+2, clamped to grid).
    if (tid < 5) {
        int j = bid - 2 + tid;
        j = j < 0 ? 0 : (j >= BLKS ? BLKS - 1 : j);
        while (__hip_atomic_load(&flags[j], __ATOMIC_ACQUIRE, __HIP_MEMORY_SCOPE_AGENT) == 0) {
            __builtin_amdgcn_s_sleep(2);
        }
    }
    __syncthreads();

    // ---------------- Phase 2a: conv7 + conv3 -> sigmoid -> w_lds ----------
    __shared__ float w_lds[PBLK];
    {
        const int hw = hwb + tid;
        const int h  = hw / Wn;
        const int w  = hw - h * Wn;
        const float* ap = avgp + b * HWn;
        const float* mp = maxp + b * HWn;

        float a7 = 0.f;
        #pragma unroll
        for (int kh = 0; kh < 7; ++kh) {
            const int hh = h + kh - 3;
            if (hh < 0 || hh >= Hn) continue;
            #pragma unroll
            for (int kw = 0; kw < 7; ++kw) {
                const int ww = w + kw - 3;
                if (ww < 0 || ww >= Wn) continue;
                const int o = hh * Wn + ww;
                const float av = __hip_atomic_load(&ap[o], __ATOMIC_RELAXED, __HIP_MEMORY_SCOPE_AGENT);
                const float mv = __hip_atomic_load(&mp[o], __ATOMIC_RELAXED, __HIP_MEMORY_SCOPE_AGENT);
                a7 = fmaf(av, w7[kh * 7 + kw], a7);
                a7 = fmaf(mv, w7[49 + kh * 7 + kw], a7);
            }
        }

        float a3 = 0.f;
        #pragma unroll
        for (int kh = 0; kh < 3; ++kh) {
            const int hh = h + kh - 1;
            if (hh < 0 || hh >= Hn) continue;
            #pragma unroll
            for (int kw = 0; kw < 3; ++kw) {
                const int ww = w + kw - 1;
                if (ww < 0 || ww >= Wn) continue;
                const int o = hh * Wn + ww;
                const float av = __hip_atomic_load(&ap[o], __ATOMIC_RELAXED, __HIP_MEMORY_SCOPE_AGENT);
                const float mv = __hip_atomic_load(&mp[o], __ATOMIC_RELAXED, __HIP_MEMORY_SCOPE_AGENT);
                a3 = fmaf(av, w3[kh * 3 + kw], a3);
                a3 = fmaf(mv, w3[9 + kh * 3 + kw], a3);
            }
        }

        const float alpha = *alphap;
        const float z = alpha * a7 + (1.0f - alpha) * a3;
        w_lds[tid] = 1.0f / (1.0f + expf(-z));
    }
    __syncthreads();

    // ---------------- Phase 2b: out = x * w (plain loads, NT stores) -------
    {
        const float4 wf = reinterpret_cast<const float4*>(w_lds)[lane];
        const v4f wvf = { wf.x, wf.y, wf.z, wf.w };
        const v4f* __restrict__ xin = reinterpret_cast<const v4f*>(x + off0);
        v4f* __restrict__ oout = reinterpret_cast<v4f*>(out + off0);

        #pragma unroll 8
        for (int c = 0; c < 64; ++c) {
            const size_t idx = ((size_t)(c0 + c) * HWn) >> 2;
            const v4f xv = xin[idx];
            __builtin_nontemporal_store(xv * wvf, oout + idx);
        }
    }
}

extern "C" void kernel_launch(void* const* d_in, const int* in_sizes, int n_in,
                              void* d_out, int out_size, void* d_ws, size_t ws_size,
                              hipStream_t stream) {
    const float* x      = (const float*)d_in[0];
    const float* w7     = (const float*)d_in[1];
    const float* w3     = (const float*)d_in[2];
    const float* alphap = (const float*)d_in[3];
    float* out = (float*)d_out;

    float* avgp = (float*)d_ws;          // NPIX floats
    float* maxp = avgp + NPIX;           // NPIX floats
    int*   flags = (int*)(maxp + NPIX);  // BLKS ints (zeroed every call)

    hipMemsetAsync(flags, 0, BLKS * sizeof(int), stream);
    k_fused<<<BLKS, 256, 0, stream>>>(x, w7, w3, alphap, avgp, maxp, flags, out);
}

// Round 10
// 137.131 us; speedup vs baseline: 1.0536x; 1.0536x over previous
//
#include <hip/hip_runtime.h>
#include <float.h>
#include <math.h>

#define Bn 8
#define Cn 256
#define Hn 160
#define Wn 160
#define HWn (Hn * Wn)          // 25600
#define NPIX (Bn * HWn)        // 204800
#define PBLK 256               // pixels per block
#define BLKS (NPIX / PBLK)     // 800

typedef float v4f __attribute__((ext_vector_type(4)));

// Fused kernel, flag-pipelined (no cooperative launch):
//  phase 1: block reduces its 256 pixels over 256 channels -> desc written
//           with agent-scope stores; release-store flag[bid].
//  wait:    acquire-spin on flag[bid-2 .. bid+2] (conv halo < 2 blocks).
//  phase 2a: cooperative COALESCED agent-scope load of the desc halo
//           (<= 9 rows x 160 x 2 planes = 11.5 KB) into LDS, then conv7+
//           conv3+sigmoid out of LDS (fixes R9's 232 scalar L3 taps/thread).
//  phase 2b: out = x*w. x re-read is L3-hot (R7/R9: FETCH == one x read);
//           NT stores keep out from evicting x.
__global__ __launch_bounds__(256) void k_fused(const float* __restrict__ x,
                                               const float* __restrict__ w7,
                                               const float* __restrict__ w3,
                                               const float* __restrict__ alphap,
                                               float* __restrict__ avgp,
                                               float* __restrict__ maxp,
                                               int* __restrict__ flags,
                                               float* __restrict__ out) {
    const int tid  = threadIdx.x;
    const int lane = tid & 63;
    const int wv   = tid >> 6;
    const int bid  = blockIdx.x;
    const int base = bid << 8;           // first pixel of this block
    const int b    = base / HWn;
    const int hwb  = base - b * HWn;
    const int c0   = wv << 6;
    const size_t off0 = (size_t)b * Cn * HWn + hwb + (lane << 2);

    // Aliased LDS: phase 1 uses ss/sm (8 KB); phase 2a reuses it as the
    // desc halo tile (avg rows then max rows, nrows each, 160 wide).
    __shared__ __align__(16) float shmem[2880];   // 11.5 KB
    __shared__ float w_lds[PBLK];
    float4* ss = reinterpret_cast<float4*>(shmem);        // [4][64]
    float4* sm = ss + 256;                                 // [4][64]

    // ---------------- Phase 1: per-pixel channel mean + max ----------------
    {
        const float* xp = x + off0;
        float4 s = make_float4(0.f, 0.f, 0.f, 0.f);
        float4 m = make_float4(-FLT_MAX, -FLT_MAX, -FLT_MAX, -FLT_MAX);
        #pragma unroll 8
        for (int c = 0; c < 64; ++c) {
            const float4 v = *reinterpret_cast<const float4*>(xp + (size_t)(c0 + c) * HWn);
            s.x += v.x; s.y += v.y; s.z += v.z; s.w += v.w;
            m.x = fmaxf(m.x, v.x); m.y = fmaxf(m.y, v.y);
            m.z = fmaxf(m.z, v.z); m.w = fmaxf(m.w, v.w);
        }

        ss[wv * 64 + lane] = s;
        sm[wv * 64 + lane] = m;
        __syncthreads();

        if (tid < 64) {
            const float4 s0 = ss[0*64+tid], s1 = ss[1*64+tid], s2 = ss[2*64+tid], s3 = ss[3*64+tid];
            const float4 m0 = sm[0*64+tid], m1 = sm[1*64+tid], m2 = sm[2*64+tid], m3 = sm[3*64+tid];
            const float inv = 1.0f / (float)Cn;
            float4 av, mx;
            av.x = (s0.x + s1.x + s2.x + s3.x) * inv;
            av.y = (s0.y + s1.y + s2.y + s3.y) * inv;
            av.z = (s0.z + s1.z + s2.z + s3.z) * inv;
            av.w = (s0.w + s1.w + s2.w + s3.w) * inv;
            mx.x = fmaxf(fmaxf(m0.x, m1.x), fmaxf(m2.x, m3.x));
            mx.y = fmaxf(fmaxf(m0.y, m1.y), fmaxf(m2.y, m3.y));
            mx.z = fmaxf(fmaxf(m0.z, m1.z), fmaxf(m2.z, m3.z));
            mx.w = fmaxf(fmaxf(m0.w, m1.w), fmaxf(m2.w, m3.w));
            const int p = base + (tid << 2);
            __hip_atomic_store(&avgp[p+0], av.x, __ATOMIC_RELAXED, __HIP_MEMORY_SCOPE_AGENT);
            __hip_atomic_store(&avgp[p+1], av.y, __ATOMIC_RELAXED, __HIP_MEMORY_SCOPE_AGENT);
            __hip_atomic_store(&avgp[p+2], av.z, __ATOMIC_RELAXED, __HIP_MEMORY_SCOPE_AGENT);
            __hip_atomic_store(&avgp[p+3], av.w, __ATOMIC_RELAXED, __HIP_MEMORY_SCOPE_AGENT);
            __hip_atomic_store(&maxp[p+0], mx.x, __ATOMIC_RELAXED, __HIP_MEMORY_SCOPE_AGENT);
            __hip_atomic_store(&maxp[p+1], mx.y, __ATOMIC_RELAXED, __HIP_MEMORY_SCOPE_AGENT);
            __hip_atomic_store(&maxp[p+2], mx.z, __ATOMIC_RELAXED, __HIP_MEMORY_SCOPE_AGENT);
            __hip_atomic_store(&maxp[p+3], mx.w, __ATOMIC_RELAXED, __HIP_MEMORY_SCOPE_AGENT);
        }
    }

    // Desc stores retired before the barrier; then release flag.
    __syncthreads();
    if (tid == 0) {
        __hip_atomic_store(&flags[bid], 1, __ATOMIC_RELEASE, __HIP_MEMORY_SCOPE_AGENT);
    }
    if (tid < 5) {
        int j = bid - 2 + tid;
        j = j < 0 ? 0 : (j >= BLKS ? BLKS - 1 : j);
        while (__hip_atomic_load(&flags[j], __ATOMIC_ACQUIRE, __HIP_MEMORY_SCOPE_AGENT) == 0) {
            __builtin_amdgcn_s_sleep(2);
        }
    }
    __syncthreads();   // also separates ss/sm reads from dtile overwrite

    // ---- Phase 2a: stage desc halo into LDS (coalesced agent loads) ----
    const int r0 = hwb / Wn;                       // first row this block touches
    const int rl = (hwb + PBLK - 1) / Wn;          // last row
    const int rs = (r0 - 3 < 0) ? 0 : r0 - 3;      // halo start row
    const int re = (rl + 3 > Hn - 1) ? Hn - 1 : rl + 3;
    const int nrows = re - rs + 1;                 // <= 9
    const int prow  = nrows * Wn;                  // floats per plane
    {
        const float* srcA = avgp + b * HWn + rs * Wn;
        const float* srcM = maxp + b * HWn + rs * Wn;
        const int total = 2 * prow;                // <= 2880
        for (int idx = tid; idx < total; idx += PBLK) {
            const int  inA = idx < prow;
            const int  o   = inA ? idx : idx - prow;
            const float* s = inA ? srcA : srcM;
            shmem[idx] = __hip_atomic_load(&s[o], __ATOMIC_RELAXED, __HIP_MEMORY_SCOPE_AGENT);
        }
    }
    __syncthreads();

    // ---- conv7 + conv3 -> sigmoid -> w_lds (taps from LDS) ----
    {
        const int hw = hwb + tid;
        const int h  = hw / Wn;
        const int w  = hw - h * Wn;

        float a7 = 0.f;
        #pragma unroll
        for (int kh = 0; kh < 7; ++kh) {
            const int hh = h + kh - 3;
            if (hh < 0 || hh >= Hn) continue;
            const float* arow = &shmem[(hh - rs) * Wn];
            const float* mrow = arow + prow;
            #pragma unroll
            for (int kw = 0; kw < 7; ++kw) {
                const int ww = w + kw - 3;
                if (ww < 0 || ww >= Wn) continue;
                a7 = fmaf(arow[ww], w7[kh * 7 + kw], a7);
                a7 = fmaf(mrow[ww], w7[49 + kh * 7 + kw], a7);
            }
        }

        float a3 = 0.f;
        #pragma unroll
        for (int kh = 0; kh < 3; ++kh) {
            const int hh = h + kh - 1;
            if (hh < 0 || hh >= Hn) continue;
            const float* arow = &shmem[(hh - rs) * Wn];
            const float* mrow = arow + prow;
            #pragma unroll
            for (int kw = 0; kw < 3; ++kw) {
                const int ww = w + kw - 1;
                if (ww < 0 || ww >= Wn) continue;
                a3 = fmaf(arow[ww], w3[kh * 3 + kw], a3);
                a3 = fmaf(mrow[ww], w3[9 + kh * 3 + kw], a3);
            }
        }

        const float alpha = *alphap;
        const float z = alpha * a7 + (1.0f - alpha) * a3;
        w_lds[tid] = 1.0f / (1.0f + expf(-z));
    }
    __syncthreads();

    // ---------------- Phase 2b: out = x * w (plain loads, NT stores) -------
    {
        const float4 wf = reinterpret_cast<const float4*>(w_lds)[lane];
        const v4f wvf = { wf.x, wf.y, wf.z, wf.w };
        const v4f* __restrict__ xin = reinterpret_cast<const v4f*>(x + off0);
        v4f* __restrict__ oout = reinterpret_cast<v4f*>(out + off0);

        #pragma unroll 8
        for (int c = 0; c < 64; ++c) {
            const size_t idx = ((size_t)(c0 + c) * HWn) >> 2;
            const v4f xv = xin[idx];
            __builtin_nontemporal_store(xv * wvf, oout + idx);
        }
    }
}

extern "C" void kernel_launch(void* const* d_in, const int* in_sizes, int n_in,
                              void* d_out, int out_size, void* d_ws, size_t ws_size,
                              hipStream_t stream) {
    const float* x      = (const float*)d_in[0];
    const float* w7     = (const float*)d_in[1];
    const float* w3     = (const float*)d_in[2];
    const float* alphap = (const float*)d_in[3];
    float* out = (float*)d_out;

    float* avgp = (float*)d_ws;          // NPIX floats
    float* maxp = avgp + NPIX;           // NPIX floats
    int*   flags = (int*)(maxp + NPIX);  // BLKS ints (zeroed every call)

    hipMemsetAsync(flags, 0, BLKS * sizeof(int), stream);
    k_fused<<<BLKS, 256, 0, stream>>>(x, w7, w3, alphap, avgp, maxp, flags, out);
}

// Round 11
// 108.684 us; speedup vs baseline: 1.3294x; 1.2617x over previous
//
#include <hip/hip_runtime.h>
#include <float.h>
#include <math.h>

#define Bn 8
#define Cn 256
#define Hn 160
#define Wn 160
#define HWn (Hn * Wn)          // 25600
#define NPIX (Bn * HWn)        // 204800
#define NTOT (Bn * Cn * HWn)   // 52428800

typedef float v4f __attribute__((ext_vector_type(4)));

// ------- Kernel 1: partial channel mean+max, 2-way channel split ---------
// 1600 blocks x 256 threads: block = (pixelBlock 0..799, half 0..1).
// Block reduces channels [half*128, half*128+128) for its 256 pixels.
// Wave wv owns 32 channels; per channel step a wave reads 64 lanes x 16B
// = 1 KB contiguous (same segment shape as the proven 112us kernel --
// R8 showed narrower segments regress). 1600 blocks = 6.25/CU doubles the
// resident-wave pool vs 800, halving exposed HBM latency.
__global__ __launch_bounds__(256) void k_reduce(const float* __restrict__ x,
                                                float* __restrict__ psum,
                                                float* __restrict__ pmax) {
    const int tid  = threadIdx.x;
    const int lane = tid & 63;
    const int wv   = tid >> 6;
    const int pb   = blockIdx.x >> 1;          // pixel block 0..799
    const int half = blockIdx.x & 1;           // channel half
    const int base = pb << 8;                  // first pixel of this block
    const int b    = base / HWn;
    const int hwb  = base - b * HWn;
    const float* xp = x + (size_t)b * Cn * HWn + hwb + (lane << 2);
    const int c0 = (half << 7) + (wv << 5);    // 32 channels per wave

    float4 s = make_float4(0.f, 0.f, 0.f, 0.f);
    float4 m = make_float4(-FLT_MAX, -FLT_MAX, -FLT_MAX, -FLT_MAX);
    #pragma unroll 16
    for (int c = 0; c < 32; ++c) {
        const float4 v = *reinterpret_cast<const float4*>(xp + (size_t)(c0 + c) * HWn);
        s.x += v.x; s.y += v.y; s.z += v.z; s.w += v.w;
        m.x = fmaxf(m.x, v.x); m.y = fmaxf(m.y, v.y);
        m.z = fmaxf(m.z, v.z); m.w = fmaxf(m.w, v.w);
    }

    __shared__ float4 ss[4][64];
    __shared__ float4 sm[4][64];
    ss[wv][lane] = s;
    sm[wv][lane] = m;
    __syncthreads();

    if (tid < 64) {
        const float4 s0 = ss[0][tid], s1 = ss[1][tid], s2 = ss[2][tid], s3 = ss[3][tid];
        const float4 m0 = sm[0][tid], m1 = sm[1][tid], m2 = sm[2][tid], m3 = sm[3][tid];
        float4 as, am;
        as.x = (s0.x + s1.x) + (s2.x + s3.x);
        as.y = (s0.y + s1.y) + (s2.y + s3.y);
        as.z = (s0.z + s1.z) + (s2.z + s3.z);
        as.w = (s0.w + s1.w) + (s2.w + s3.w);
        am.x = fmaxf(fmaxf(m0.x, m1.x), fmaxf(m2.x, m3.x));
        am.y = fmaxf(fmaxf(m0.y, m1.y), fmaxf(m2.y, m3.y));
        am.z = fmaxf(fmaxf(m0.z, m1.z), fmaxf(m2.z, m3.z));
        am.w = fmaxf(fmaxf(m0.w, m1.w), fmaxf(m2.w, m3.w));
        reinterpret_cast<float4*>(psum + (size_t)half * NPIX)[(base >> 2) + tid] = as;
        reinterpret_cast<float4*>(pmax + (size_t)half * NPIX)[(base >> 2) + tid] = am;
    }
}

// ------- Kernel 2: combine partials + 7x7 & 3x3 conv + sigmoid -----------
// 800 blocks x 256 threads; block owns 256 consecutive pixels. Halo desc
// rows (<=9 rows x 160 x 2 planes) staged through LDS with coalesced loads,
// combining the two channel-half partials on the fly (sources ~6.4 MB,
// L2/L3-hot). Conv taps from LDS. Zero padding == skip OOB taps;
// lax.conv is cross-correlation.
__global__ __launch_bounds__(256) void k_conv(const float* __restrict__ psum,
                                              const float* __restrict__ pmax,
                                              const float* __restrict__ w7,
                                              const float* __restrict__ w3,
                                              const float* __restrict__ alphap,
                                              float* __restrict__ wmap) {
    __shared__ float shmem[2880];     // avg rows then max rows, <=9x160 each
    __shared__ float dummy_pad;       // (keep LDS layout simple)

    const int tid  = threadIdx.x;
    const int base = blockIdx.x << 8;
    const int b    = base / HWn;
    const int hwb  = base - b * HWn;

    const int r0 = hwb / Wn;
    const int rl = (hwb + 255) / Wn;
    const int rs = (r0 - 3 < 0) ? 0 : r0 - 3;
    const int re = (rl + 3 > Hn - 1) ? Hn - 1 : rl + 3;
    const int nrows = re - rs + 1;                 // <= 9
    const int prow  = nrows * Wn;

    {
        const size_t bofs = (size_t)b * HWn + rs * Wn;
        const float* s0 = psum + bofs;
        const float* s1 = psum + NPIX + bofs;
        const float* m0 = pmax + bofs;
        const float* m1 = pmax + NPIX + bofs;
        const float inv = 1.0f / (float)Cn;
        const int total = 2 * prow;
        for (int idx = tid; idx < total; idx += 256) {
            if (idx < prow) {
                shmem[idx] = (s0[idx] + s1[idx]) * inv;
            } else {
                const int o = idx - prow;
                shmem[idx] = fmaxf(m0[o], m1[o]);
            }
        }
    }
    __syncthreads();

    {
        const int hw = hwb + tid;
        const int h  = hw / Wn;
        const int w  = hw - h * Wn;

        float a7 = 0.f;
        #pragma unroll
        for (int kh = 0; kh < 7; ++kh) {
            const int hh = h + kh - 3;
            if (hh < 0 || hh >= Hn) continue;
            const float* arow = &shmem[(hh - rs) * Wn];
            const float* mrow = arow + prow;
            #pragma unroll
            for (int kw = 0; kw < 7; ++kw) {
                const int ww = w + kw - 3;
                if (ww < 0 || ww >= Wn) continue;
                a7 = fmaf(arow[ww], w7[kh * 7 + kw], a7);
                a7 = fmaf(mrow[ww], w7[49 + kh * 7 + kw], a7);
            }
        }

        float a3 = 0.f;
        #pragma unroll
        for (int kh = 0; kh < 3; ++kh) {
            const int hh = h + kh - 1;
            if (hh < 0 || hh >= Hn) continue;
            const float* arow = &shmem[(hh - rs) * Wn];
            const float* mrow = arow + prow;
            #pragma unroll
            for (int kw = 0; kw < 3; ++kw) {
                const int ww = w + kw - 1;
                if (ww < 0 || ww >= Wn) continue;
                a3 = fmaf(arow[ww], w3[kh * 3 + kw], a3);
                a3 = fmaf(mrow[ww], w3[9 + kh * 3 + kw], a3);
            }
        }

        const float alpha = *alphap;
        const float z = alpha * a7 + (1.0f - alpha) * a3;
        wmap[base + tid] = 1.0f / (1.0f + expf(-z));
        (void)dummy_pad;
    }
}

// ------- Kernel 3: out = x * w, channel-sweep form ------------------------
// 1600 blocks x 256 threads; block owns 128 pixels (32 float4 strips).
// Thread (g = tid&31, cs = tid>>5): strip g, channels [cs*32, cs*32+32).
// w float4 loaded ONCE into registers; inner loop is pure
// load -> mul -> NT-store at fixed stride (no div/mod, no wmap reload).
// x re-read is L3-hot (R7/R9/R10: FETCH == one x read); NT stores keep
// out from evicting x. Plain x loads (NT loads regressed in R6).
__global__ __launch_bounds__(256) void k_mul(const float* __restrict__ x,
                                             const float* __restrict__ wmap,
                                             float* __restrict__ out) {
    const int tid  = threadIdx.x;
    const int g    = tid & 31;           // float4 strip within 128 px
    const int cs   = tid >> 5;           // channel subset 0..7
    const int base = blockIdx.x << 7;    // first pixel (HWn % 128 == 0)
    const int b    = base / HWn;
    const int hwb  = base - b * HWn;

    const float4 wf = reinterpret_cast<const float4*>(wmap)[(base >> 2) + g];
    const v4f wvf = { wf.x, wf.y, wf.z, wf.w };

    const size_t off0 = (size_t)b * Cn * HWn + hwb + (g << 2);
    const v4f* __restrict__ xin = reinterpret_cast<const v4f*>(x + off0);
    v4f* __restrict__ oout = reinterpret_cast<v4f*>(out + off0);
    const int c0 = cs << 5;

    #pragma unroll 8
    for (int k = 0; k < 32; ++k) {
        const size_t idx = (size_t)(c0 + k) * (HWn / 4);
        const v4f xv = xin[idx];
        __builtin_nontemporal_store(xv * wvf, oout + idx);
    }
}

extern "C" void kernel_launch(void* const* d_in, const int* in_sizes, int n_in,
                              void* d_out, int out_size, void* d_ws, size_t ws_size,
                              hipStream_t stream) {
    const float* x      = (const float*)d_in[0];
    const float* w7     = (const float*)d_in[1];
    const float* w3     = (const float*)d_in[2];
    const float* alphap = (const float*)d_in[3];
    float* out = (float*)d_out;

    float* psum = (float*)d_ws;              // 2 * NPIX floats (two halves)
    float* pmax = psum + 2 * NPIX;           // 2 * NPIX floats
    float* wmap = pmax + 2 * NPIX;           // NPIX floats   (total 4.0 MB)

    k_reduce<<<1600, 256, 0, stream>>>(x, psum, pmax);
    k_conv  <<<800,  256, 0, stream>>>(psum, pmax, w7, w3, alphap, wmap);
    k_mul   <<<1600, 256, 0, stream>>>(x, wmap, out);
}

// Round 12
// 107.671 us; speedup vs baseline: 1.3419x; 1.0094x over previous
//
#include <hip/hip_runtime.h>
#include <float.h>
#include <math.h>

#define Bn 8
#define Cn 256
#define Hn 160
#define Wn 160
#define HWn (Hn * Wn)          // 25600
#define NPIX (Bn * HWn)        // 204800
#define NTOT (Bn * Cn * HWn)   // 52428800

typedef float v4f __attribute__((ext_vector_type(4)));

// ------- Kernel 1: partial channel mean+max, 4-way channel split ---------
// 3200 blocks x 256 threads: block = (pixelBlock 0..799, quarter 0..3).
// Block reduces channels [q*64, q*64+64) for its 256 pixels. Wave wv owns
// 16 channels; per channel step a wave reads 64 lanes x 16B = 1 KB
// contiguous (proven segment shape; R8 showed narrower segments regress).
// 3200 blocks = 12.5/CU for maximum latency hiding.
__global__ __launch_bounds__(256) void k_reduce(const float* __restrict__ x,
                                                float* __restrict__ psum,
                                                float* __restrict__ pmax) {
    const int tid  = threadIdx.x;
    const int lane = tid & 63;
    const int wv   = tid >> 6;
    const int pb   = blockIdx.x >> 2;          // pixel block 0..799
    const int q    = blockIdx.x & 3;           // channel quarter
    const int base = pb << 8;                  // first pixel of this block
    const int b    = base / HWn;
    const int hwb  = base - b * HWn;
    const float* xp = x + (size_t)b * Cn * HWn + hwb + (lane << 2);
    const int c0 = (q << 6) + (wv << 4);       // 16 channels per wave

    float4 s = make_float4(0.f, 0.f, 0.f, 0.f);
    float4 m = make_float4(-FLT_MAX, -FLT_MAX, -FLT_MAX, -FLT_MAX);
    #pragma unroll
    for (int c = 0; c < 16; ++c) {
        const float4 v = *reinterpret_cast<const float4*>(xp + (size_t)(c0 + c) * HWn);
        s.x += v.x; s.y += v.y; s.z += v.z; s.w += v.w;
        m.x = fmaxf(m.x, v.x); m.y = fmaxf(m.y, v.y);
        m.z = fmaxf(m.z, v.z); m.w = fmaxf(m.w, v.w);
    }

    __shared__ float4 ss[4][64];
    __shared__ float4 sm[4][64];
    ss[wv][lane] = s;
    sm[wv][lane] = m;
    __syncthreads();

    if (tid < 64) {
        const float4 s0 = ss[0][tid], s1 = ss[1][tid], s2 = ss[2][tid], s3 = ss[3][tid];
        const float4 m0 = sm[0][tid], m1 = sm[1][tid], m2 = sm[2][tid], m3 = sm[3][tid];
        float4 as, am;
        as.x = (s0.x + s1.x) + (s2.x + s3.x);
        as.y = (s0.y + s1.y) + (s2.y + s3.y);
        as.z = (s0.z + s1.z) + (s2.z + s3.z);
        as.w = (s0.w + s1.w) + (s2.w + s3.w);
        am.x = fmaxf(fmaxf(m0.x, m1.x), fmaxf(m2.x, m3.x));
        am.y = fmaxf(fmaxf(m0.y, m1.y), fmaxf(m2.y, m3.y));
        am.z = fmaxf(fmaxf(m0.z, m1.z), fmaxf(m2.z, m3.z));
        am.w = fmaxf(fmaxf(m0.w, m1.w), fmaxf(m2.w, m3.w));
        reinterpret_cast<float4*>(psum + (size_t)q * NPIX)[(base >> 2) + tid] = as;
        reinterpret_cast<float4*>(pmax + (size_t)q * NPIX)[(base >> 2) + tid] = am;
    }
}

// ------- Kernel 2: combine 4 partials + 7x7 & 3x3 conv + sigmoid ---------
// 800 blocks x 256 threads; block owns 256 consecutive pixels. Halo desc
// rows (<=9 rows x 160 x 2 planes) staged through LDS with coalesced loads,
// combining the four channel-quarter partials on the fly (sources ~13 MB,
// L2/L3-hot). Conv taps from LDS. Zero padding == skip OOB taps;
// lax.conv is cross-correlation.
__global__ __launch_bounds__(256) void k_conv(const float* __restrict__ psum,
                                              const float* __restrict__ pmax,
                                              const float* __restrict__ w7,
                                              const float* __restrict__ w3,
                                              const float* __restrict__ alphap,
                                              float* __restrict__ wmap) {
    __shared__ float shmem[2880];     // avg rows then max rows, <=9x160 each

    const int tid  = threadIdx.x;
    const int base = blockIdx.x << 8;
    const int b    = base / HWn;
    const int hwb  = base - b * HWn;

    const int r0 = hwb / Wn;
    const int rl = (hwb + 255) / Wn;
    const int rs = (r0 - 3 < 0) ? 0 : r0 - 3;
    const int re = (rl + 3 > Hn - 1) ? Hn - 1 : rl + 3;
    const int nrows = re - rs + 1;                 // <= 9
    const int prow  = nrows * Wn;

    {
        const size_t bofs = (size_t)b * HWn + rs * Wn;
        const float* s0 = psum + bofs;
        const float* s1 = psum + (size_t)1 * NPIX + bofs;
        const float* s2 = psum + (size_t)2 * NPIX + bofs;
        const float* s3 = psum + (size_t)3 * NPIX + bofs;
        const float* m0 = pmax + bofs;
        const float* m1 = pmax + (size_t)1 * NPIX + bofs;
        const float* m2 = pmax + (size_t)2 * NPIX + bofs;
        const float* m3 = pmax + (size_t)3 * NPIX + bofs;
        const float inv = 1.0f / (float)Cn;
        const int total = 2 * prow;
        for (int idx = tid; idx < total; idx += 256) {
            if (idx < prow) {
                shmem[idx] = ((s0[idx] + s1[idx]) + (s2[idx] + s3[idx])) * inv;
            } else {
                const int o = idx - prow;
                shmem[idx] = fmaxf(fmaxf(m0[o], m1[o]), fmaxf(m2[o], m3[o]));
            }
        }
    }
    __syncthreads();

    {
        const int hw = hwb + tid;
        const int h  = hw / Wn;
        const int w  = hw - h * Wn;

        float a7 = 0.f;
        #pragma unroll
        for (int kh = 0; kh < 7; ++kh) {
            const int hh = h + kh - 3;
            if (hh < 0 || hh >= Hn) continue;
            const float* arow = &shmem[(hh - rs) * Wn];
            const float* mrow = arow + prow;
            #pragma unroll
            for (int kw = 0; kw < 7; ++kw) {
                const int ww = w + kw - 3;
                if (ww < 0 || ww >= Wn) continue;
                a7 = fmaf(arow[ww], w7[kh * 7 + kw], a7);
                a7 = fmaf(mrow[ww], w7[49 + kh * 7 + kw], a7);
            }
        }

        float a3 = 0.f;
        #pragma unroll
        for (int kh = 0; kh < 3; ++kh) {
            const int hh = h + kh - 1;
            if (hh < 0 || hh >= Hn) continue;
            const float* arow = &shmem[(hh - rs) * Wn];
            const float* mrow = arow + prow;
            #pragma unroll
            for (int kw = 0; kw < 3; ++kw) {
                const int ww = w + kw - 1;
                if (ww < 0 || ww >= Wn) continue;
                a3 = fmaf(arow[ww], w3[kh * 3 + kw], a3);
                a3 = fmaf(mrow[ww], w3[9 + kh * 3 + kw], a3);
            }
        }

        const float alpha = *alphap;
        const float z = alpha * a7 + (1.0f - alpha) * a3;
        wmap[base + tid] = 1.0f / (1.0f + expf(-z));
    }
}

// ------- Kernel 3: out = x * w, channel-sweep, 2-way channel split -------
// 3200 blocks x 256 threads: block = (strip 0..1599, half 0..1); strip owns
// 128 consecutive pixels (32 float4). Thread (g = tid&31, cs = tid>>5):
// f4-group g, channels [half*128 + cs*16, +16). Wave = 2 x 512 B segments
// per step (proven shape). w float4 in registers; inner loop is pure
// load -> mul -> NT-store at fixed stride. NT stores: out never re-read.
__global__ __launch_bounds__(256) void k_mul(const float* __restrict__ x,
                                             const float* __restrict__ wmap,
                                             float* __restrict__ out) {
    const int tid   = threadIdx.x;
    const int g     = tid & 31;           // float4 strip within 128 px
    const int cs    = tid >> 5;           // channel subset 0..7
    const int strip = blockIdx.x >> 1;
    const int half  = blockIdx.x & 1;
    const int base  = strip << 7;         // first pixel (HWn % 128 == 0)
    const int b     = base / HWn;
    const int hwb   = base - b * HWn;

    const float4 wf = reinterpret_cast<const float4*>(wmap)[(base >> 2) + g];
    const v4f wvf = { wf.x, wf.y, wf.z, wf.w };

    const size_t off0 = (size_t)b * Cn * HWn + hwb + (g << 2);
    const v4f* __restrict__ xin = reinterpret_cast<const v4f*>(x + off0);
    v4f* __restrict__ oout = reinterpret_cast<v4f*>(out + off0);
    const int c0 = (half << 7) + (cs << 4);   // 16 channels

    #pragma unroll
    for (int k = 0; k < 16; ++k) {
        const size_t idx = (size_t)(c0 + k) * (HWn / 4);
        const v4f xv = xin[idx];
        __builtin_nontemporal_store(xv * wvf, oout + idx);
    }
}

extern "C" void kernel_launch(void* const* d_in, const int* in_sizes, int n_in,
                              void* d_out, int out_size, void* d_ws, size_t ws_size,
                              hipStream_t stream) {
    const float* x      = (const float*)d_in[0];
    const float* w7     = (const float*)d_in[1];
    const float* w3     = (const float*)d_in[2];
    const float* alphap = (const float*)d_in[3];
    float* out = (float*)d_out;

    float* psum = (float*)d_ws;              // 4 * NPIX floats (quarters)
    float* pmax = psum + 4 * NPIX;           // 4 * NPIX floats
    float* wmap = pmax + 4 * NPIX;           // NPIX floats   (total 7.4 MB)

    k_reduce<<<3200, 256, 0, stream>>>(x, psum, pmax);
    k_conv  <<<800,  256, 0, stream>>>(psum, pmax, w7, w3, alphap, wmap);
    k_mul   <<<3200, 256, 0, stream>>>(x, wmap, out);
}